// Round 3
// baseline (602.858 us; speedup 1.0000x reference)
//
#include <hip/hip_runtime.h>
#include <hip/hip_bf16.h>
#include <math.h>

// ---------------------------------------------------------------------------
// SelfAttn2d: out = x + gamma * (V @ softmax(Q K^T / sqrt(32))^T)
// B=4, C=256, N=4096, D=32.
// Round 3: occupancy + latency-hiding round.
//  - attn: 512 thr (8 waves), 2 n-groups per block, K/V register prefetch.
//  - qk_proj: 256 blocks, 4 wave-groups splitting the 64 outputs.
//  - sigma: ONE kernel (3 blocks): blocks 0/1 = qk 32x32 chain (VALU),
//           block 2 = wv 256x256 Gram^64 chain on MFMA in LDS.
// ---------------------------------------------------------------------------

#define NPOS 4096
#define WROW 264   // padded bf16 row stride for 256x256 LDS matrix (conflict-free b128)

typedef __bf16 bf16x8 __attribute__((ext_vector_type(8)));
typedef float  f32x16 __attribute__((ext_vector_type(16)));

static __device__ inline unsigned int pk2(float a, float b) {
    union { __hip_bfloat16 h[2]; unsigned int u; } x;
    x.h[0] = __float2bfloat16(a);
    x.h[1] = __float2bfloat16(b);
    return x.u;
}

// ---------------------------------------------------------------------------
// sigma_all: block 0 -> sigma(wq), block 1 -> sigma(wk), block 2 -> sigma(wv).
// 512 threads.
// ---------------------------------------------------------------------------
__global__ __launch_bounds__(512) void sigma_all(const float* __restrict__ wq,
                                                 const float* __restrict__ wk,
                                                 const float* __restrict__ wv,
                                                 float* __restrict__ scal) {
    __shared__ __align__(16) __hip_bfloat16 Wsh[256 * WROW];  // 132 KB
    __shared__ float red[512];
    __shared__ float trsh;
    __shared__ float xv[256];

    int t = threadIdx.x;

    if (blockIdx.x < 2) {
        // ---------------- qk path: 32x256 -> Gram 32x32 chain (fp32 VALU) ----
        const float* w = (blockIdx.x == 0) ? wq : wk;
        float* F  = (float*)Wsh;
        float* Ws = F;                 // [32][257]
        float* G  = F + 32 * 257;      // [32][33]
        float* A  = G + 32 * 33;
        float* Bt = A + 32 * 33;
        float* xq = Bt + 32 * 33;      // [32]
        float* yq = xq + 32;           // [32]

        if (t < 256) {
            for (int i = 0; i < 32; i++) {
                int idx = t + 256 * i;
                Ws[(idx >> 8) * 257 + (idx & 255)] = w[idx];
            }
        }
        __syncthreads();
        if (t < 256) {
            for (int i = 0; i < 4; i++) {
                int id = t + 256 * i;
                int r = id >> 5, cc = id & 31;
                float s = 0.f;
                for (int c = 0; c < 256; c++) s += Ws[r * 257 + c] * Ws[cc * 257 + c];
                G[r * 33 + cc] = s;
                A[r * 33 + cc] = s;
            }
        }
        __syncthreads();
        for (int sq = 0; sq < 8; sq++) {
            if (t == 0) {
                float tr = 0.f;
                for (int i = 0; i < 32; i++) tr += A[i * 33 + i];
                trsh = 1.0f / tr;
            }
            __syncthreads();
            float invt = trsh;
            if (t < 256) {
                for (int i = 0; i < 4; i++) {
                    int id = t + 256 * i;
                    int r = id >> 5, cc = id & 31;
                    float s = 0.f;
                    #pragma unroll
                    for (int k2 = 0; k2 < 32; k2++) s += A[r * 33 + k2] * A[cc * 33 + k2];
                    Bt[r * 33 + cc] = s * invt * invt;
                }
            }
            __syncthreads();
            if (t < 256) {
                for (int i = 0; i < 4; i++) {
                    int id = t + 256 * i;
                    A[(id >> 5) * 33 + (id & 31)] = Bt[(id >> 5) * 33 + (id & 31)];
                }
            }
            __syncthreads();
        }
        if (t < 32) xq[t] = 1.0f + 0.01f * t;
        __syncthreads();
        for (int it = 0; it < 4; it++) {
            if (t < 32) {
                float y = 0.f;
                #pragma unroll
                for (int j = 0; j < 32; j++) y += A[t * 33 + j] * xq[j];
                yq[t] = y;
            }
            __syncthreads();
            if (t < 32) {
                float ss = 0.f;
                #pragma unroll
                for (int j = 0; j < 32; j++) ss += yq[j] * yq[j];
                xq[t] = yq[t] * rsqrtf(ss);
            }
            __syncthreads();
        }
        if (t == 0) {
            float lam = 0.f;
            for (int i = 0; i < 32; i++) {
                float y = 0.f;
                for (int j = 0; j < 32; j++) y += G[i * 33 + j] * xq[j];
                lam += xq[i] * y;
            }
            scal[blockIdx.x] = rsqrtf(lam);
        }
        return;
    }

    // ---------------- v path: 256x256 Gram^64 chain on MFMA ------------------
    int wave = t >> 6, lane = t & 63, lo = lane & 31, hi = lane >> 5;
    int p = wave >> 1;   // m-tile pair index (m-tiles 2p, 2p+1)
    int q = wave & 1;    // j-quad index (j-tiles 4q..4q+3)

    // stage wv fp32 -> bf16 LDS (coalesced global, strided writes)
    for (int i = 0; i < 128; i++) {
        int idx = t + 512 * i;
        Wsh[(idx >> 8) * WROW + (idx & 255)] = __float2bfloat16(wv[idx]);
    }
    __syncthreads();

    // 7 rounds: round 0: C = W W^T (Gram); rounds 1..6: C = A A^T = A^2.
    // Each round trace-normalizes: A' = C / tr(C) (keeps bf16 in range).
    for (int round = 0; round < 7; round++) {
        f32x16 c[2][4];
        #pragma unroll
        for (int mt = 0; mt < 2; mt++)
            #pragma unroll
            for (int j = 0; j < 4; j++)
                #pragma unroll
                for (int r = 0; r < 16; r++) c[mt][j][r] = 0.f;

        for (int kc = 0; kc < 16; kc++) {
            bf16x8 af[2], bfj[4];
            #pragma unroll
            for (int mt = 0; mt < 2; mt++)
                af[mt] = *(const bf16x8*)&Wsh[((2 * p + mt) * 32 + lo) * WROW + kc * 16 + hi * 8];
            #pragma unroll
            for (int j = 0; j < 4; j++)
                bfj[j] = *(const bf16x8*)&Wsh[((4 * q + j) * 32 + lo) * WROW + kc * 16 + hi * 8];
            #pragma unroll
            for (int mt = 0; mt < 2; mt++)
                #pragma unroll
                for (int j = 0; j < 4; j++)
                    c[mt][j] = __builtin_amdgcn_mfma_f32_32x32x16_bf16(af[mt], bfj[j], c[mt][j], 0, 0, 0);
        }

        // trace of C from diagonal tiles
        float dsum = 0.f;
        #pragma unroll
        for (int mt = 0; mt < 2; mt++) {
            int Tm = 2 * p + mt;
            if ((Tm >> 2) == q) {
                int j = Tm - 4 * q;
                #pragma unroll
                for (int r = 0; r < 16; r++) {
                    int row = (r & 3) + 8 * (r >> 2) + 4 * hi;
                    if (row == lo) dsum += c[mt][j][r];
                }
            }
        }
        red[t] = dsum;
        __syncthreads();   // also guarantees all MFMA reads of Wsh are done
        for (int s2 = 256; s2 > 0; s2 >>= 1) {
            if (t < s2) red[t] += red[t + s2];
            __syncthreads();
        }
        float invt = 1.0f / red[0];
        __syncthreads();

        // write back normalized bf16 (in place)
        #pragma unroll
        for (int mt = 0; mt < 2; mt++)
            #pragma unroll
            for (int j = 0; j < 4; j++)
                #pragma unroll
                for (int r = 0; r < 16; r++) {
                    int row = (2 * p + mt) * 32 + (r & 3) + 8 * (r >> 2) + 4 * hi;
                    int col = (4 * q + j) * 32 + lo;
                    Wsh[row * WROW + col] = __float2bfloat16(c[mt][j][r] * invt);
                }
        __syncthreads();
    }

    // 8 power iterations: x <- normalize(A x), A = G^64 (bf16 LDS)
    if (t < 256) xv[t] = 1.0f + 0.01f * t;
    __syncthreads();
    for (int it = 0; it < 8; it++) {
        float y = 0.f;
        if (t < 256) {
            for (int ch = 0; ch < 32; ch++) {
                bf16x8 a = *(const bf16x8*)&Wsh[t * WROW + ch * 8];
                #pragma unroll
                for (int e = 0; e < 8; e++) y += (float)a[e] * xv[ch * 8 + e];
            }
        }
        red[t] = (t < 256) ? y * y : 0.f;
        __syncthreads();
        for (int s2 = 256; s2 > 0; s2 >>= 1) {
            if (t < s2) red[t] += red[t + s2];
            __syncthreads();
        }
        if (t == 0) trsh = rsqrtf(red[0]);
        __syncthreads();
        if (t < 256) xv[t] = y * trsh;
        __syncthreads();
    }

    // Rayleigh in fp32 against exact G: lambda = x^T G x = ||wv^T x||^2
    float z = 0.f;
    if (t < 256) {
        for (int i = 0; i < 256; i++) z += wv[i * 256 + t] * xv[i];
    }
    red[t] = (t < 256) ? z * z : 0.f;
    __syncthreads();
    for (int s2 = 256; s2 > 0; s2 >>= 1) {
        if (t < s2) red[t] += red[t + s2];
        __syncthreads();
    }
    if (t == 0) scal[2] = rsqrtf(red[0]);
}

// ---------------------------------------------------------------------------
// qk_proj: qT[b][n][32], kT[b][n][32] bf16 (raw; sigma folded into attn).
// 256 thr: wave-group grp (t>>6): 0=q[0:16) 1=q[16:32) 2=k[0:16) 3=k[16:32).
// Groups re-read the same x column -> L1 hits. unroll 4 -> load ILP.
// ---------------------------------------------------------------------------
__global__ __launch_bounds__(256) void qk_proj(const float* __restrict__ x,
                                               const float* __restrict__ wq,
                                               const float* __restrict__ wk,
                                               __hip_bfloat16* __restrict__ qT,
                                               __hip_bfloat16* __restrict__ kT) {
    int t = threadIdx.x;
    int nl = t & 63, grp = t >> 6;
    int n = blockIdx.x * 64 + nl;
    int b = blockIdx.y;
    const float* xb = x + ((size_t)b << 20);
    const float* wbase = ((grp & 2) ? wk : wq) + (grp & 1) * 16 * 256;

    float a[16];
    #pragma unroll
    for (int r = 0; r < 16; r++) a[r] = 0.f;
    #pragma unroll 4
    for (int c = 0; c < 256; c++) {
        float xvv = xb[(size_t)c * NPOS + n];
        #pragma unroll
        for (int r = 0; r < 16; r++) a[r] += wbase[r * 256 + c] * xvv;
    }
    __hip_bfloat16* dst = ((grp & 2) ? kT : qT) + ((size_t)b * NPOS + n) * 32 + (grp & 1) * 16;
    uint4 u0, u1;
    u0.x = pk2(a[0], a[1]);   u0.y = pk2(a[2], a[3]);
    u0.z = pk2(a[4], a[5]);   u0.w = pk2(a[6], a[7]);
    u1.x = pk2(a[8], a[9]);   u1.y = pk2(a[10], a[11]);
    u1.z = pk2(a[12], a[13]); u1.w = pk2(a[14], a[15]);
    *(uint4*)dst = u0;
    *(uint4*)(dst + 8) = u1;
}

// ---------------------------------------------------------------------------
// v_proj: v[b][e][n] bf16 (raw wv @ x; sigma_v folded into attn epilogue).
// ---------------------------------------------------------------------------
__global__ __launch_bounds__(256) void v_proj(const float* __restrict__ x,
                                              const float* __restrict__ wv,
                                              __hip_bfloat16* __restrict__ v) {
    int n = blockIdx.x * 256 + threadIdx.x;
    int e0 = blockIdx.y * 16;
    int b = blockIdx.z;
    const float* xb = x + ((size_t)b << 20);
    float acc[16];
    #pragma unroll
    for (int r = 0; r < 16; r++) acc[r] = 0.f;
    #pragma unroll 4
    for (int c = 0; c < 256; c++) {
        float xvv = xb[(size_t)c * NPOS + n];
        #pragma unroll
        for (int r = 0; r < 16; r++) acc[r] += wv[(e0 + r) * 256 + c] * xvv;
    }
    #pragma unroll
    for (int r = 0; r < 16; r++)
        v[((size_t)b * 256 + e0 + r) * NPOS + n] = __float2bfloat16(acc[r]);
}

// ---------------------------------------------------------------------------
// MFMA flash attention. 512 thr (8 waves), Mq=64 per block, grid 256.
// Wave-group g = wave>>2 handles n-steps n0 = 128*s + 64*g (own Plds, own
// acc/L). Within a group, waves (wv4): S-quadrant (mtile=wv4>>1, ntile=wv4&1),
// PV e-range wv4*64. K/V fragments for step s+1 are prefetched into registers
// before the PV phase of step s (global latency hides under exp+barrier+MFMA).
// Group partials merged via LDS at the end; epilogue split: group g stores
// e-half g. No max-subtraction (spectral norm bounds logits).
// ---------------------------------------------------------------------------
__global__ __launch_bounds__(512) void attn_mfma(const float* __restrict__ x,
                                                 const __hip_bfloat16* __restrict__ qT,
                                                 const __hip_bfloat16* __restrict__ kT,
                                                 const __hip_bfloat16* __restrict__ v,
                                                 const float* __restrict__ scal,
                                                 const float* __restrict__ gam,
                                                 float* __restrict__ out) {
    __shared__ __hip_bfloat16 Plds[2][64 * 72];   // per-group P, stride 72 (conflict-free)
    __shared__ float4 xbuf[2][4][2][4][64];       // 64 KB merge buffer
    __shared__ float Lpart[8][32];

    int t = threadIdx.x;
    int wave = t >> 6, lane = t & 63;
    int lo = lane & 31, hi = lane >> 5;
    int g = wave >> 2, wv4 = wave & 3;

    // XCD swizzle: batch b pinned to XCD pair (perf heuristic only)
    int blk = blockIdx.x;
    int x8 = blk & 7;
    int b = x8 >> 1;
    int m0 = (((x8 & 1) << 5) + (blk >> 3)) << 6;

    const __hip_bfloat16* qTb = qT + ((size_t)b << 17);
    const __hip_bfloat16* kTb = kT + ((size_t)b << 17);
    const __hip_bfloat16* vb  = v  + ((size_t)b << 20);

    int mtile_s = wv4 >> 1, ntile_s = wv4 & 1;
    int e0w = wv4 << 6;
    float qkscale = scal[0] * scal[1] * 0.17677669529663687f;  // sq*sk/sqrt(32)

    bf16x8 qf0 = *(const bf16x8*)(qTb + (size_t)(m0 + mtile_s * 32 + lo) * 32 + hi * 8);
    bf16x8 qf1 = *(const bf16x8*)(qTb + (size_t)(m0 + mtile_s * 32 + lo) * 32 + 16 + hi * 8);

    f32x16 acc[2][2];
    #pragma unroll
    for (int et = 0; et < 2; et++)
        #pragma unroll
        for (int mt = 0; mt < 2; mt++)
            #pragma unroll
            for (int r = 0; r < 16; r++) acc[et][mt][r] = 0.f;
    float l_acc = 0.f;

    const __hip_bfloat16* kaddr0 = kTb + (size_t)(ntile_s * 32 + lo) * 32 + hi * 8;
    const __hip_bfloat16* va0b = vb + (size_t)(e0w + lo) * NPOS + hi * 8;
    const __hip_bfloat16* va1b = vb + (size_t)(e0w + 32 + lo) * NPOS + hi * 8;

    bf16x8 kf[2][2], vf[2][8];
    {
        int n0 = 64 * g;
        kf[0][0] = *(const bf16x8*)(kaddr0 + (size_t)n0 * 32);
        kf[0][1] = *(const bf16x8*)(kaddr0 + (size_t)n0 * 32 + 16);
        #pragma unroll
        for (int kc = 0; kc < 4; kc++) {
            vf[0][2 * kc]     = *(const bf16x8*)(va0b + n0 + kc * 16);
            vf[0][2 * kc + 1] = *(const bf16x8*)(va1b + n0 + kc * 16);
        }
    }

    __hip_bfloat16* Pg = Plds[g];

    #pragma unroll 2
    for (int s = 0; s < 32; s++) {
        int cur = s & 1, nxt = cur ^ 1;
        int n0 = 128 * s + 64 * g;

        // ---- S^T = K Q^T via MFMA (rows=n, cols=m) ----
        f32x16 sv;
        #pragma unroll
        for (int r = 0; r < 16; r++) sv[r] = 0.f;
        sv = __builtin_amdgcn_mfma_f32_32x32x16_bf16(kf[cur][0], qf0, sv, 0, 0, 0);
        sv = __builtin_amdgcn_mfma_f32_32x32x16_bf16(kf[cur][1], qf1, sv, 0, 0, 0);

        // ---- prefetch next step's K/V into registers ----
        if (s < 31) {
            int n1 = n0 + 128;
            kf[nxt][0] = *(const bf16x8*)(kaddr0 + (size_t)n1 * 32);
            kf[nxt][1] = *(const bf16x8*)(kaddr0 + (size_t)n1 * 32 + 16);
            #pragma unroll
            for (int kc = 0; kc < 4; kc++) {
                vf[nxt][2 * kc]     = *(const bf16x8*)(va0b + n1 + kc * 16);
                vf[nxt][2 * kc + 1] = *(const bf16x8*)(va1b + n1 + kc * 16);
            }
        }

        __syncthreads();  // prior PV reads of Plds done (both groups)
        int mrow = mtile_s * 32 + lo;
        #pragma unroll
        for (int gg = 0; gg < 4; gg++) {
            float p0 = __expf(sv[4 * gg + 0] * qkscale);
            float p1 = __expf(sv[4 * gg + 1] * qkscale);
            float p2 = __expf(sv[4 * gg + 2] * qkscale);
            float p3 = __expf(sv[4 * gg + 3] * qkscale);
            l_acc += (p0 + p1) + (p2 + p3);
            uint2 pk;
            pk.x = pk2(p0, p1);
            pk.y = pk2(p2, p3);
            *(uint2*)(&Pg[mrow * 72 + ntile_s * 32 + 8 * gg + 4 * hi]) = pk;
        }
        __syncthreads();  // P ready

        // ---- PV: V (regs) x P (LDS) ----
        #pragma unroll
        for (int kc = 0; kc < 4; kc++) {
            bf16x8 pf0 = *(const bf16x8*)(&Pg[lo * 72 + kc * 16 + hi * 8]);
            bf16x8 pf1 = *(const bf16x8*)(&Pg[(32 + lo) * 72 + kc * 16 + hi * 8]);
            acc[0][0] = __builtin_amdgcn_mfma_f32_32x32x16_bf16(vf[cur][2 * kc],     pf0, acc[0][0], 0, 0, 0);
            acc[0][1] = __builtin_amdgcn_mfma_f32_32x32x16_bf16(vf[cur][2 * kc],     pf1, acc[0][1], 0, 0, 0);
            acc[1][0] = __builtin_amdgcn_mfma_f32_32x32x16_bf16(vf[cur][2 * kc + 1], pf0, acc[1][0], 0, 0, 0);
            acc[1][1] = __builtin_amdgcn_mfma_f32_32x32x16_bf16(vf[cur][2 * kc + 1], pf1, acc[1][1], 0, 0, 0);
        }
    }

    // ---- L partials (lane ^32 holds same m, other n-half) ----
    float lsum = l_acc + __shfl_xor(l_acc, 32, 64);
    if (lane < 32) Lpart[wave][lane] = lsum;

    // ---- cross-group acc merge: group g keeps et=g, ships et=1-g ----
    #pragma unroll
    for (int mt = 0; mt < 2; mt++)
        #pragma unroll
        for (int r4 = 0; r4 < 4; r4++) {
            float4 vq;
            vq.x = acc[1 - g][mt][4 * r4 + 0];
            vq.y = acc[1 - g][mt][4 * r4 + 1];
            vq.z = acc[1 - g][mt][4 * r4 + 2];
            vq.w = acc[1 - g][mt][4 * r4 + 3];
            xbuf[g][wv4][mt][r4][lane] = vq;
        }
    __syncthreads();
    #pragma unroll
    for (int mt = 0; mt < 2; mt++)
        #pragma unroll
        for (int r4 = 0; r4 < 4; r4++) {
            float4 vq = xbuf[1 - g][wv4][mt][r4][lane];
            acc[g][mt][4 * r4 + 0] += vq.x;
            acc[g][mt][4 * r4 + 1] += vq.y;
            acc[g][mt][4 * r4 + 2] += vq.z;
            acc[g][mt][4 * r4 + 3] += vq.w;
        }

    // ---- epilogue: out = x + gamma*sig_v * acc / L ----
    float gs = gam[0] * scal[2];
    const float* xb = x + ((size_t)b << 20);
    float* ob = out + ((size_t)b << 20);
    #pragma unroll
    for (int mt = 0; mt < 2; mt++) {
        float L = Lpart[2 * mt][lo] + Lpart[2 * mt + 1][lo] +
                  Lpart[4 + 2 * mt][lo] + Lpart[4 + 2 * mt + 1][lo];
        float f = gs / L;
        int m = m0 + mt * 32 + lo;
        #pragma unroll
        for (int r = 0; r < 16; r++) {
            int e = e0w + g * 32 + (r & 3) + 8 * (r >> 2) + 4 * hi;
            size_t idx = (size_t)e * NPOS + m;
            ob[idx] = xb[idx] + f * acc[g][mt][r];
        }
    }
}

// ---------------------------------------------------------------------------
extern "C" void kernel_launch(void* const* d_in, const int* in_sizes, int n_in,
                              void* d_out, int out_size, void* d_ws, size_t ws_size,
                              hipStream_t stream) {
    const float* x     = (const float*)d_in[0];
    const float* wq    = (const float*)d_in[1];
    const float* wk    = (const float*)d_in[2];
    const float* wv    = (const float*)d_in[3];
    const float* gamma = (const float*)d_in[4];
    float* out = (float*)d_out;

    char* wsb = (char*)d_ws;
    float* scal = (float*)wsb;                          // [0..63]
    __hip_bfloat16* qT = (__hip_bfloat16*)(wsb + 256);
    __hip_bfloat16* kT = qT + (size_t)4 * NPOS * 32;
    __hip_bfloat16* vp = kT + (size_t)4 * NPOS * 32;    // 4*256*4096 bf16

    qk_proj<<<dim3(64, 4), 256, 0, stream>>>(x, wq, wk, qT, kT);
    v_proj<<<dim3(16, 16, 4), 256, 0, stream>>>(x, wv, vp);
    sigma_all<<<3, 512, 0, stream>>>(wq, wk, wv, scal);
    attn_mfma<<<256, 512, 0, stream>>>(x, qT, kT, vp, scal, gamma, out);
}